// Round 1
// baseline (2134.214 us; speedup 1.0000x reference)
//
#include <hip/hip_runtime.h>
#include <math.h>

// Fused 3-layer LSTM + dense head, fp32 throughout.
// B=2048, T=256, F=64, H0=64, H1=32, H2=16, OUT=1.
//
// Strategy: persistent fused kernel. Each block owns BT=4 batch elements and
// iterates t=0..255 with all layer state in LDS/registers. All weights
// (47,872 floats total) live in per-thread REGISTERS (each thread owns a
// gate-column slice), loaded once from L2 at kernel start -> zero per-step
// weight traffic. Activations are broadcast from LDS with uniform-address
// float4 reads (conflict-free broadcast).
//
// Thread roles (256 threads/block):
//   layer0 z: thread t owns gate-col t of 4H=256; weights W0[:,t],U0[:,t] = 128 regs
//   layer1 z: col = t&127, k-half = t>>7; 48 regs of [W1;U1][:,col]
//   layer2 z: col = t&63, k-quarter = t>>6; 12 regs of [W2;U2][:,col]
//   gates l0: (b = t>>6, hh = t&63)  -> c0 in reg
//   gates l1: t<128: (b = t>>5, hh = t&31) -> c1 in reg
//   gates l2: t<64:  (b = t>>4, hh = t&15) -> c2 in reg

#define BT 4
#define THREADS 256
#define T_STEPS 256

__device__ __forceinline__ float sigmoid_f(float x) {
    return 1.0f / (1.0f + __expf(-x));
}
__device__ __forceinline__ float tanh_f(float x) {
    // stable both directions: exp overflow -> inf -> 1; underflow -> 0 -> -1
    return 1.0f - 2.0f / (__expf(2.0f * x) + 1.0f);
}

__global__ __launch_bounds__(THREADS, 2)
void lstm_fused(const float* __restrict__ x,
                const float* __restrict__ W0, const float* __restrict__ U0, const float* __restrict__ b0,
                const float* __restrict__ W1, const float* __restrict__ U1, const float* __restrict__ b1,
                const float* __restrict__ W2, const float* __restrict__ U2, const float* __restrict__ b2,
                const float* __restrict__ Wd, const float* __restrict__ bd,
                float* __restrict__ out)
{
    const int t = threadIdx.x;
    const int bbase = blockIdx.x * BT;

    __shared__ __align__(16) float a0[BT][128];    // [x_t(64) | h0(64)]
    __shared__ __align__(16) float a1[BT][96];     // [h0(64) | h1(32)]
    __shared__ __align__(16) float a2[BT][48];     // [h1(32) | h2(16)]
    __shared__ __align__(16) float zbuf[BT * 256]; // l0 z / l1 partials / l2 partials

    // ---------------- weights -> registers ----------------
    float V0r[128];
#pragma unroll
    for (int k = 0; k < 64; ++k) V0r[k]      = W0[k * 256 + t];
#pragma unroll
    for (int k = 0; k < 64; ++k) V0r[64 + k] = U0[k * 256 + t];
    const float b0r = b0[t];

    const int col1 = t & 127;
    const int sel1 = t >> 7;            // k-half for layer1
    float V1r[48];
#pragma unroll
    for (int j = 0; j < 48; ++j) {
        int r = sel1 * 48 + j;          // row in [W1(64); U1(32)]
        V1r[j] = (r < 64) ? W1[r * 128 + col1] : U1[(r - 64) * 128 + col1];
    }
    const float b1r = sel1 ? 0.0f : b1[col1];

    const int col2 = t & 63;
    const int sel2 = t >> 6;            // k-quarter for layer2 (0..3)
    float V2r[12];
#pragma unroll
    for (int j = 0; j < 12; ++j) {
        int r = sel2 * 12 + j;          // row in [W2(32); U2(16)]
        V2r[j] = (r < 32) ? W2[r * 64 + col2] : U2[(r - 32) * 64 + col2];
    }
    const float b2r = (sel2 == 0) ? b2[col2] : 0.0f;

    // ---------------- init state ----------------
    float c0 = 0.0f, c1 = 0.0f, c2 = 0.0f;
    {   // zero the h regions read on the first step
        int b = t >> 6, i = t & 63;
        a0[b][64 + i] = 0.0f;                       // h0 region (256 slots)
        if (t < 128) a1[t >> 5][64 + (t & 31)] = 0.0f;  // h1 region
        if (t < 64)  a2[t >> 4][32 + (t & 15)] = 0.0f;  // h2 region
    }
    __syncthreads();

    const float* xbase = x + (size_t)bbase * T_STEPS * 64;

    const int bA = t >> 6, fA = t & 63;     // x-load role
    const int bC = t >> 6, hhC = t & 63;    // gates0 role

    for (int step = 0; step < T_STEPS; ++step) {
        // (A) stage x_t : [BT][64]
        a0[bA][fA] = xbase[((size_t)bA * T_STEPS + step) * 64 + fA];
        __syncthreads();

        // (B) layer0 z: z[b][t] = b0 + [x|h0] . V0col(t)
#pragma unroll
        for (int b = 0; b < BT; ++b) {
            float acc = b0r;
#pragma unroll
            for (int k = 0; k < 128; k += 4) {
                float4 v = *(const float4*)&a0[b][k];   // uniform addr -> broadcast
                acc += v.x * V0r[k] + v.y * V0r[k + 1] + v.z * V0r[k + 2] + v.w * V0r[k + 3];
            }
            zbuf[b * 256 + t] = acc;
        }
        __syncthreads();

        // (C) layer0 gates
        {
            float zi = zbuf[bC * 256 + hhC];
            float zf = zbuf[bC * 256 + 64 + hhC];
            float zg = zbuf[bC * 256 + 128 + hhC];
            float zo = zbuf[bC * 256 + 192 + hhC];
            float ig = sigmoid_f(zi);
            float fg = sigmoid_f(zf);
            float gg = tanh_f(zg);
            float og = sigmoid_f(zo);
            c0 = fg * c0 + ig * gg;
            float h = og * tanh_f(c0);
            a0[bC][64 + hhC] = h;
            a1[bC][hhC]      = h;
        }
        __syncthreads();

        // (D) layer1 z partials: rows [48*sel1, 48*sel1+48) of [h0|h1].V1
        {
            const int ko = sel1 * 48;
#pragma unroll
            for (int b = 0; b < BT; ++b) {
                float acc = b1r;
#pragma unroll
                for (int j = 0; j < 48; j += 4) {
                    float4 v = *(const float4*)&a1[b][ko + j];
                    acc += v.x * V1r[j] + v.y * V1r[j + 1] + v.z * V1r[j + 2] + v.w * V1r[j + 3];
                }
                zbuf[sel1 * 512 + b * 128 + col1] = acc;
            }
        }
        __syncthreads();

        // (E) layer1 gates (threads 0..127)
        if (t < 128) {
            int b = t >> 5, hh = t & 31;
            float z0g = zbuf[b * 128 + hh]       + zbuf[512 + b * 128 + hh];
            float z1g = zbuf[b * 128 + 32 + hh]  + zbuf[512 + b * 128 + 32 + hh];
            float z2g = zbuf[b * 128 + 64 + hh]  + zbuf[512 + b * 128 + 64 + hh];
            float z3g = zbuf[b * 128 + 96 + hh]  + zbuf[512 + b * 128 + 96 + hh];
            float ig = sigmoid_f(z0g);
            float fg = sigmoid_f(z1g);
            float gg = tanh_f(z2g);
            float og = sigmoid_f(z3g);
            c1 = fg * c1 + ig * gg;
            float h = og * tanh_f(c1);
            a1[b][64 + hh] = h;
            a2[b][hh]      = h;
        }
        __syncthreads();

        // (F) layer2 z partials: rows [12*sel2, 12*sel2+12) of [h1|h2].V2
        {
            const int ko = sel2 * 12;
#pragma unroll
            for (int b = 0; b < BT; ++b) {
                float acc = b2r;
#pragma unroll
                for (int j = 0; j < 12; j += 4) {
                    float4 v = *(const float4*)&a2[b][ko + j];
                    acc += v.x * V2r[j] + v.y * V2r[j + 1] + v.z * V2r[j + 2] + v.w * V2r[j + 3];
                }
                zbuf[sel2 * 256 + b * 64 + col2] = acc;
            }
        }
        __syncthreads();

        // (G) layer2 gates (threads 0..63)
        if (t < 64) {
            int b = t >> 4, hh = t & 15;
            float zg4[4];
#pragma unroll
            for (int g = 0; g < 4; ++g) {
                int o = b * 64 + g * 16 + hh;
                zg4[g] = zbuf[o] + zbuf[256 + o] + zbuf[512 + o] + zbuf[768 + o];
            }
            float ig = sigmoid_f(zg4[0]);
            float fg = sigmoid_f(zg4[1]);
            float gg = tanh_f(zg4[2]);
            float og = sigmoid_f(zg4[3]);
            c2 = fg * c2 + ig * gg;
            float h = og * tanh_f(c2);
            a2[b][32 + hh] = h;
        }
        __syncthreads();
    }

    // (H) dense head: out[b] = h2_last . Wd + bd
    if (t < BT) {
        float acc = bd[0];
#pragma unroll
        for (int j = 0; j < 16; ++j) acc += a2[t][32 + j] * Wd[j];
        out[bbase + t] = acc;
    }
}

extern "C" void kernel_launch(void* const* d_in, const int* in_sizes, int n_in,
                              void* d_out, int out_size, void* d_ws, size_t ws_size,
                              hipStream_t stream) {
    (void)in_sizes; (void)n_in; (void)d_ws; (void)ws_size; (void)out_size;
    const float* x  = (const float*)d_in[0];
    const float* W0 = (const float*)d_in[1];
    const float* U0 = (const float*)d_in[2];
    const float* b0 = (const float*)d_in[3];
    const float* W1 = (const float*)d_in[4];
    const float* U1 = (const float*)d_in[5];
    const float* b1 = (const float*)d_in[6];
    const float* W2 = (const float*)d_in[7];
    const float* U2 = (const float*)d_in[8];
    const float* b2 = (const float*)d_in[9];
    const float* Wd = (const float*)d_in[10];
    const float* bd = (const float*)d_in[11];
    float* out = (float*)d_out;

    dim3 grid(2048 / BT);      // 512 blocks
    dim3 block(THREADS);
    hipLaunchKernelGGL(lstm_fused, grid, block, 0, stream,
                       x, W0, U0, b0, W1, U1, b1, W2, U2, b2, Wd, bd, out);
}

// Round 2
// 709.299 us; speedup vs baseline: 3.0089x; 3.0089x over previous
//
#include <hip/hip_runtime.h>

// Fused 3-layer LSTM + dense head via bf16-split MFMA.
// B=2048, T=256, F=64, H=[64,32,16], OUT=1. fp32 in/out.
//
// Each product a*w is computed as ah*wh + al*wh + ah*wl with a=ah+al bf16
// split (effective ~2^-16 relative precision, fp32 accumulate in MFMA).
// Weights live pre-split in per-lane B-fragment REGISTERS (loaded once).
// Activations staged in LDS in exact A-fragment order so each wave reads
// them with contiguous ds_read_b128 (no broadcast waste, no conflicts).
//
// Block: 256 threads = 4 waves, BT=8 batch rows (MFMA M=16, rows 8..15 zero).
// Grid: 256 blocks = 1 block/CU.
//
// Staging chunks (each [16 rows][32 k] in frag order, bf16 hi & lo):
//   c0: x[0:32]   c1: x[32:64]   c2: h0[0:32]  c3: h0[32:64]
//   c4: h1[0:32]  c5: h2[0:16] + zero pad[16:32]
//   A0 (L0, K=128) = c0..c3;  A1 (L1, K=96) = c2..c4;  A2 (L2, K=64p) = c4..c5

typedef __attribute__((ext_vector_type(8))) short s8v;   // 8 x bf16
typedef __attribute__((ext_vector_type(4))) float f4v;   // 4 x f32

#define T_STEPS 256
#define BT 8

__device__ __forceinline__ unsigned short f2bf(float f) {
    unsigned u = __float_as_uint(f);
    u += 0x7fff + ((u >> 16) & 1);          // round-to-nearest-even
    return (unsigned short)(u >> 16);
}
__device__ __forceinline__ float bf2f(unsigned short s) {
    return __uint_as_float(((unsigned)s) << 16);
}
__device__ __forceinline__ float sigmoid_f(float x) { return 1.0f / (1.0f + __expf(-x)); }
__device__ __forceinline__ float tanh_f(float x)    { return 1.0f - 2.0f / (__expf(2.0f * x) + 1.0f); }

// combined [W;U] weight matrix element, zero-padded past KH rows
__device__ __forceinline__ float wval(const float* W, const float* U,
                                      int inDim, int KH, int fourH, int k, int n) {
    if (k < inDim) return W[k * fourH + n];
    if (k < KH)    return U[(k - inDim) * fourH + n];
    return 0.0f;
}

__device__ __forceinline__ void load_bfrag(const float* W, const float* U,
                                           int inDim, int KH, int fourH,
                                           int k0, int n, s8v& hi, s8v& lo) {
#pragma unroll
    for (int j = 0; j < 8; ++j) {
        float w = wval(W, U, inDim, KH, fourH, k0 + j, n);
        unsigned short h = f2bf(w);
        unsigned short l = f2bf(w - bf2f(h));
        hi[j] = (short)h;
        lo[j] = (short)l;
    }
}

__global__ __launch_bounds__(256, 1)
void lstm_mfma(const float* __restrict__ x,
               const float* __restrict__ W0, const float* __restrict__ U0, const float* __restrict__ b0,
               const float* __restrict__ W1, const float* __restrict__ U1, const float* __restrict__ b1,
               const float* __restrict__ W2, const float* __restrict__ U2, const float* __restrict__ b2,
               const float* __restrict__ Wd, const float* __restrict__ bd,
               float* __restrict__ out)
{
    const int tid  = threadIdx.x;
    const int lane = tid & 63;
    const int wv   = tid >> 6;          // wave 0..3
    const int fr   = lane >> 4;         // frag k-group 0..3
    const int fc   = lane & 15;         // frag n (B) / m (A) / col (C)
    const int bbase = blockIdx.x * BT;

    __shared__ __align__(16) unsigned short Shi[6][16 * 32];
    __shared__ __align__(16) unsigned short Slo[6][16 * 32];
    __shared__ __align__(16) float z0[BT][256];
    __shared__ __align__(16) float z1[BT][128];
    __shared__ __align__(16) float z2[BT][64];
    __shared__ __align__(16) float h2f[BT][16];

    // ---------------- weights -> register B-fragments (hi/lo) ----------------
    s8v B0h[4][4], B0l[4][4];           // [q (Nc=4w+q)][Kc]
    float bias0[4];
#pragma unroll
    for (int q = 0; q < 4; ++q) {
        int n = (4 * wv + q) * 16 + fc;
        bias0[q] = b0[n];
#pragma unroll
        for (int kc = 0; kc < 4; ++kc)
            load_bfrag(W0, U0, 64, 128, 256, kc * 32 + fr * 8, n, B0h[q][kc], B0l[q][kc]);
    }
    s8v B1h[2][3], B1l[2][3];           // [q (Nc=2w+q)][Kc]
    float bias1[2];
#pragma unroll
    for (int q = 0; q < 2; ++q) {
        int n = (2 * wv + q) * 16 + fc;
        bias1[q] = b1[n];
#pragma unroll
        for (int kc = 0; kc < 3; ++kc)
            load_bfrag(W1, U1, 64, 96, 128, kc * 32 + fr * 8, n, B1h[q][kc], B1l[q][kc]);
    }
    s8v B2h[2], B2l[2];                 // Nc = wv
    float bias2;
    {
        int n = wv * 16 + fc;
        bias2 = b2[n];
#pragma unroll
        for (int kc = 0; kc < 2; ++kc)
            load_bfrag(W2, U2, 32, 48, 64, kc * 32 + fr * 8, n, B2h[kc], B2l[kc]);
    }

    // ---------------- zero staging (h init = 0, pad = 0) ----------------
    {
        unsigned* ph = (unsigned*)&Shi[0][0];
        unsigned* pl = (unsigned*)&Slo[0][0];
#pragma unroll
        for (int i = 0; i < 6; ++i) { ph[tid + 256 * i] = 0u; pl[tid + 256 * i] = 0u; }
    }

    float c0a = 0.0f, c0b = 0.0f;       // layer0 cell state (2 h per thread)
    float c1 = 0.0f, c2 = 0.0f;

    // x staging role: row xr (batch), k-pair xk
    const int xr = tid >> 5;            // 0..7
    const int xk = (tid & 31) * 2;      // 0,2,..,62
    const float* xptr = x + (size_t)(bbase + xr) * T_STEPS * 64 + xk;
    float2 xv = *(const float2*)xptr;   // step 0 prefetch

    __syncthreads();

    for (int step = 0; step < T_STEPS; ++step) {
        // ---- W0: stage x_t (bf16 hi/lo, frag order) ----
        {
            unsigned short xh0 = f2bf(xv.x);
            unsigned short xl0 = f2bf(xv.x - bf2f(xh0));
            unsigned short xh1 = f2bf(xv.y);
            unsigned short xl1 = f2bf(xv.y - bf2f(xh1));
            int chunk = xk >> 5;
            int kc = xk & 31;
            int idx = ((kc >> 3) * 16 + xr) * 8 + (kc & 7);   // even
            *(unsigned*)&Shi[chunk][idx] = (unsigned)xh0 | ((unsigned)xh1 << 16);
            *(unsigned*)&Slo[chunk][idx] = (unsigned)xl0 | ((unsigned)xl1 << 16);
        }
        if (step + 1 < T_STEPS) xv = *(const float2*)(xptr + (size_t)(step + 1) * 64);
        __syncthreads();    // B1: x_t staged

        // ---- M0: z0 = [x|h0] . V0  (16x256, K=128) ----
        {
            s8v ah[4], al[4];
#pragma unroll
            for (int kc = 0; kc < 4; ++kc) {
                ah[kc] = *(const s8v*)&Shi[kc][lane * 8];
                al[kc] = *(const s8v*)&Slo[kc][lane * 8];
            }
#pragma unroll
            for (int q = 0; q < 4; ++q) {
                f4v acc = { bias0[q], bias0[q], bias0[q], bias0[q] };
#pragma unroll
                for (int kc = 0; kc < 4; ++kc) {
                    acc = __builtin_amdgcn_mfma_f32_16x16x32_bf16(ah[kc], B0h[q][kc], acc, 0, 0, 0);
                    acc = __builtin_amdgcn_mfma_f32_16x16x32_bf16(al[kc], B0h[q][kc], acc, 0, 0, 0);
                    acc = __builtin_amdgcn_mfma_f32_16x16x32_bf16(ah[kc], B0l[q][kc], acc, 0, 0, 0);
                }
                if (lane < 32) {                       // rows 0..7 valid
                    int row0 = fr * 4;
                    int col = (4 * wv + q) * 16 + fc;
#pragma unroll
                    for (int r = 0; r < 4; ++r) z0[row0 + r][col] = acc[r];
                }
            }
        }
        __syncthreads();    // B2: z0 ready, chunks 2,3 reads done

        // ---- G0: layer0 gates, write h0 -> chunks 2,3 ----
        {
            const int b = xr;
            const int hh = xk;
            float2 zi = *(const float2*)&z0[b][0 * 64 + hh];
            float2 zf = *(const float2*)&z0[b][1 * 64 + hh];
            float2 zg = *(const float2*)&z0[b][2 * 64 + hh];
            float2 zo = *(const float2*)&z0[b][3 * 64 + hh];
            float i0 = sigmoid_f(zi.x), i1 = sigmoid_f(zi.y);
            float f0 = sigmoid_f(zf.x), f1 = sigmoid_f(zf.y);
            float g0 = tanh_f(zg.x),    g1 = tanh_f(zg.y);
            float o0 = sigmoid_f(zo.x), o1 = sigmoid_f(zo.y);
            c0a = f0 * c0a + i0 * g0;
            c0b = f1 * c0b + i1 * g1;
            float ha = o0 * tanh_f(c0a);
            float hb = o1 * tanh_f(c0b);
            unsigned short ha_h = f2bf(ha), ha_l = f2bf(ha - bf2f(ha_h));
            unsigned short hb_h = f2bf(hb), hb_l = f2bf(hb - bf2f(hb_h));
            int chunk = 2 + (hh >> 5);
            int kc = hh & 31;
            int idx = ((kc >> 3) * 16 + b) * 8 + (kc & 7);
            *(unsigned*)&Shi[chunk][idx] = (unsigned)ha_h | ((unsigned)hb_h << 16);
            *(unsigned*)&Slo[chunk][idx] = (unsigned)ha_l | ((unsigned)hb_l << 16);
        }
        __syncthreads();    // B3: h0_t staged

        // ---- M1: z1 = [h0|h1] . V1  (16x128, K=96) ----
        {
            s8v ah[3], al[3];
#pragma unroll
            for (int kc = 0; kc < 3; ++kc) {
                ah[kc] = *(const s8v*)&Shi[2 + kc][lane * 8];
                al[kc] = *(const s8v*)&Slo[2 + kc][lane * 8];
            }
#pragma unroll
            for (int q = 0; q < 2; ++q) {
                f4v acc = { bias1[q], bias1[q], bias1[q], bias1[q] };
#pragma unroll
                for (int kc = 0; kc < 3; ++kc) {
                    acc = __builtin_amdgcn_mfma_f32_16x16x32_bf16(ah[kc], B1h[q][kc], acc, 0, 0, 0);
                    acc = __builtin_amdgcn_mfma_f32_16x16x32_bf16(al[kc], B1h[q][kc], acc, 0, 0, 0);
                    acc = __builtin_amdgcn_mfma_f32_16x16x32_bf16(ah[kc], B1l[q][kc], acc, 0, 0, 0);
                }
                if (lane < 32) {
                    int row0 = fr * 4;
                    int col = (2 * wv + q) * 16 + fc;
#pragma unroll
                    for (int r = 0; r < 4; ++r) z1[row0 + r][col] = acc[r];
                }
            }
        }
        __syncthreads();    // B4: z1 ready, chunk 4 reads done

        // ---- G1: layer1 gates, write h1 -> chunk 4 ----
        {
            const int b = tid >> 5;
            const int hh = tid & 31;
            float ig = sigmoid_f(z1[b][0 * 32 + hh]);
            float fg = sigmoid_f(z1[b][1 * 32 + hh]);
            float gg = tanh_f(z1[b][2 * 32 + hh]);
            float og = sigmoid_f(z1[b][3 * 32 + hh]);
            c1 = fg * c1 + ig * gg;
            float h = og * tanh_f(c1);
            unsigned short h_h = f2bf(h), h_l = f2bf(h - bf2f(h_h));
            int idx = ((hh >> 3) * 16 + b) * 8 + (hh & 7);
            Shi[4][idx] = h_h;
            Slo[4][idx] = h_l;
        }
        __syncthreads();    // B5: h1_t staged

        // ---- M2: z2 = [h1|h2|pad] . V2  (16x64, K=64 padded) ----
        {
            s8v ah[2], al[2];
#pragma unroll
            for (int kc = 0; kc < 2; ++kc) {
                ah[kc] = *(const s8v*)&Shi[4 + kc][lane * 8];
                al[kc] = *(const s8v*)&Slo[4 + kc][lane * 8];
            }
            f4v acc = { bias2, bias2, bias2, bias2 };
#pragma unroll
            for (int kc = 0; kc < 2; ++kc) {
                acc = __builtin_amdgcn_mfma_f32_16x16x32_bf16(ah[kc], B2h[kc], acc, 0, 0, 0);
                acc = __builtin_amdgcn_mfma_f32_16x16x32_bf16(al[kc], B2h[kc], acc, 0, 0, 0);
                acc = __builtin_amdgcn_mfma_f32_16x16x32_bf16(ah[kc], B2l[kc], acc, 0, 0, 0);
            }
            if (lane < 32) {
                int row0 = fr * 4;
                int col = wv * 16 + fc;
#pragma unroll
                for (int r = 0; r < 4; ++r) z2[row0 + r][col] = acc[r];
            }
        }
        __syncthreads();    // B6: z2 ready, chunk 5 reads done

        // ---- G2: layer2 gates, write h2 -> chunk 5 + h2f ----
        if (tid < 128) {
            const int b = tid >> 4;
            const int hh = tid & 15;
            float ig = sigmoid_f(z2[b][0 * 16 + hh]);
            float fg = sigmoid_f(z2[b][1 * 16 + hh]);
            float gg = tanh_f(z2[b][2 * 16 + hh]);
            float og = sigmoid_f(z2[b][3 * 16 + hh]);
            c2 = fg * c2 + ig * gg;
            float h = og * tanh_f(c2);
            unsigned short h_h = f2bf(h), h_l = f2bf(h - bf2f(h_h));
            int idx = ((hh >> 3) * 16 + b) * 8 + (hh & 7);
            Shi[5][idx] = h_h;
            Slo[5][idx] = h_l;
            h2f[b][hh] = h;
        }
        // no barrier needed: next-step writes (chunks 0,1) are disjoint from
        // G2's chunk 5; all readers of chunk 5 are gated behind B1..B5.
    }

    __syncthreads();
    // ---- dense head ----
    if (tid < BT) {
        float acc = bd[0];
#pragma unroll
        for (int j = 0; j < 16; ++j) acc += h2f[tid][j] * Wd[j];
        out[bbase + tid] = acc;
    }
}

extern "C" void kernel_launch(void* const* d_in, const int* in_sizes, int n_in,
                              void* d_out, int out_size, void* d_ws, size_t ws_size,
                              hipStream_t stream) {
    (void)in_sizes; (void)n_in; (void)d_ws; (void)ws_size; (void)out_size;
    const float* x  = (const float*)d_in[0];
    const float* W0 = (const float*)d_in[1];
    const float* U0 = (const float*)d_in[2];
    const float* b0 = (const float*)d_in[3];
    const float* W1 = (const float*)d_in[4];
    const float* U1 = (const float*)d_in[5];
    const float* b1 = (const float*)d_in[6];
    const float* W2 = (const float*)d_in[7];
    const float* U2 = (const float*)d_in[8];
    const float* b2 = (const float*)d_in[9];
    const float* Wd = (const float*)d_in[10];
    const float* bd = (const float*)d_in[11];
    float* out = (float*)d_out;

    dim3 grid(2048 / BT);   // 256 blocks, 1 per CU
    dim3 block(256);
    hipLaunchKernelGGL(lstm_mfma, grid, block, 0, stream,
                       x, W0, U0, b0, W1, U1, b1, W2, U2, b2, Wd, bd, out);
}

// Round 3
// 636.579 us; speedup vs baseline: 3.3526x; 1.1142x over previous
//
#include <hip/hip_runtime.h>

// Fused 3-layer LSTM + dense head, layer-pipelined wave specialization.
// B=2048, T=256, F=64, H=[64,32,16], OUT=1. fp32 in/out.
//
// bf16 3-term split MFMA (ah*wh + al*wh + ah*wl) for ~2^-16 precision.
// Block = 512 threads = 8 waves, grid = 256 (1 block/CU, BT=8 batches).
//   waves 0-3 : layer0 at step t   (wave wv owns gates i,f,g,o of h0-units wv*16+fc)
//   waves 4-5 : layer1 at step t-1 (h1-half wv&1)
//   wave  6   : layer2 at step t-2
//   wave  7   : stages x(t+1) -> LDS (bf16 hi/lo, A-fragment order)
// ONE barrier per step. All activation buffers double-buffered by step parity:
// iteration s reads parity p=s&1, writes 1-p. Gates are computed directly from
// MFMA accumulators (C-layout: row=fr*4+r=batch, col=fc -> gate tiles g*H+unit),
// so no z round-trip through LDS at all.

typedef __attribute__((ext_vector_type(8))) short s8v;   // 8 x bf16
typedef __attribute__((ext_vector_type(4))) float f4v;   // 4 x f32
typedef unsigned short ushort_t;

#define T_STEPS 256
#define BT 8

// SMEM layout (units: shorts). chunk = [kgrp 0..3][row 0..15][j 0..7] = 512 shorts.
#define XH  0       // [par][2 chunks]  -> 2048
#define XL  2048
#define H0H 4096    // [par][2 chunks]  -> 2048
#define H0L 6144
#define H1H 8192    // [par][1 chunk]   -> 1024
#define H1L 9216
#define H2H 10240   // [par][1 chunk]   -> 1024 (k 16..31 = zero pad)
#define H2L 11264
#define SM_SHORTS 12288

__device__ __forceinline__ unsigned short f2bf(float f) {
    unsigned u = __float_as_uint(f);
    u += 0x7fff + ((u >> 16) & 1);          // round-to-nearest-even
    return (unsigned short)(u >> 16);
}
__device__ __forceinline__ float bf2f(unsigned short s) {
    return __uint_as_float(((unsigned)s) << 16);
}
__device__ __forceinline__ float sigmoid_f(float x) { return 1.0f / (1.0f + __expf(-x)); }
__device__ __forceinline__ float tanh_f(float x)    { return 1.0f - 2.0f / (__expf(2.0f * x) + 1.0f); }

// combined [W;U] weight element, zero-padded past KH rows
__device__ __forceinline__ float wval(const float* W, const float* U,
                                      int inDim, int KH, int fourH, int k, int n) {
    if (k < inDim) return W[k * fourH + n];
    if (k < KH)    return U[(k - inDim) * fourH + n];
    return 0.0f;
}
__device__ __forceinline__ void load_bfrag(const float* W, const float* U,
                                           int inDim, int KH, int fourH,
                                           int k0, int n, s8v& hi, s8v& lo) {
#pragma unroll
    for (int j = 0; j < 8; ++j) {
        float w = wval(W, U, inDim, KH, fourH, k0 + j, n);
        unsigned short h = f2bf(w);
        unsigned short l = f2bf(w - bf2f(h));
        hi[j] = (short)h;
        lo[j] = (short)l;
    }
}

__device__ __forceinline__ void gates4(const f4v* acc, float* c, float* hn) {
#pragma unroll
    for (int r = 0; r < 4; ++r) {
        float ig = sigmoid_f(acc[0][r]);
        float fg = sigmoid_f(acc[1][r]);
        float gg = tanh_f(acc[2][r]);
        float og = sigmoid_f(acc[3][r]);
        c[r] = fg * c[r] + ig * gg;
        hn[r] = og * tanh_f(c[r]);
    }
}

// write 4 batch-rows of one h-unit (k-position k in a chunk) as bf16 hi/lo
__device__ __forceinline__ void write_h(ushort_t* dh, ushort_t* dl, int k, int fr,
                                        const float* hn) {
    if (fr < 2) {
        int ib = (k >> 3) * 128 + (k & 7);
#pragma unroll
        for (int r = 0; r < 4; ++r) {
            int b = fr * 4 + r;
            unsigned short hh_ = f2bf(hn[r]);
            dh[ib + b * 8] = hh_;
            dl[ib + b * 8] = f2bf(hn[r] - bf2f(hh_));
        }
    }
}

__global__ __launch_bounds__(512, 2)
void lstm_pipe(const float* __restrict__ x,
               const float* __restrict__ W0, const float* __restrict__ U0, const float* __restrict__ b0,
               const float* __restrict__ W1, const float* __restrict__ U1, const float* __restrict__ b1,
               const float* __restrict__ W2, const float* __restrict__ U2, const float* __restrict__ b2,
               const float* __restrict__ Wd, const float* __restrict__ bd,
               float* __restrict__ out)
{
    const int tid  = threadIdx.x;
    const int lane = tid & 63;
    const int wv   = tid >> 6;          // 0..7
    const int fr   = lane >> 4;         // k-group / C row-group
    const int fc   = lane & 15;         // frag column
    const int bbase = blockIdx.x * BT;

    __shared__ __align__(16) ushort_t SMEM[SM_SHORTS];
    __shared__ __align__(16) float h2last[BT][16];

    // zero all staging (rows 8..15 of every chunk must stay zero; h init = 0)
    {
        unsigned* p32 = (unsigned*)SMEM;
        for (int i = tid; i < SM_SHORTS / 2; i += 512) p32[i] = 0u;
    }
    __syncthreads();                                    // barrier #1 (all waves)

    if (wv < 4) {
        // =================== layer0 role (waves 0..3) ===================
        s8v Bh[4][4], Bl[4][4];                         // [gate][kc]
        float bias[4];
#pragma unroll
        for (int g = 0; g < 4; ++g) {
            int n = g * 64 + wv * 16 + fc;
            bias[g] = b0[n];
#pragma unroll
            for (int kc = 0; kc < 4; ++kc)
                load_bfrag(W0, U0, 64, 128, 256, kc * 32 + fr * 8, n, Bh[g][kc], Bl[g][kc]);
        }
        float c0[4] = {0.f, 0.f, 0.f, 0.f};
        __syncthreads();                                // barrier #2
        for (int s = 0; s < T_STEPS + 2; ++s) {
            if (s < T_STEPS) {
                int p = s & 1;
                s8v ah[4], al[4];
                ah[0] = *(const s8v*)&SMEM[XH  + (p * 2 + 0) * 512 + lane * 8];
                al[0] = *(const s8v*)&SMEM[XL  + (p * 2 + 0) * 512 + lane * 8];
                ah[1] = *(const s8v*)&SMEM[XH  + (p * 2 + 1) * 512 + lane * 8];
                al[1] = *(const s8v*)&SMEM[XL  + (p * 2 + 1) * 512 + lane * 8];
                ah[2] = *(const s8v*)&SMEM[H0H + (p * 2 + 0) * 512 + lane * 8];
                al[2] = *(const s8v*)&SMEM[H0L + (p * 2 + 0) * 512 + lane * 8];
                ah[3] = *(const s8v*)&SMEM[H0H + (p * 2 + 1) * 512 + lane * 8];
                al[3] = *(const s8v*)&SMEM[H0L + (p * 2 + 1) * 512 + lane * 8];
                f4v acc[4];
#pragma unroll
                for (int g = 0; g < 4; ++g) acc[g] = (f4v){bias[g], bias[g], bias[g], bias[g]};
#pragma unroll
                for (int kc = 0; kc < 4; ++kc)
#pragma unroll
                    for (int g = 0; g < 4; ++g) {
                        acc[g] = __builtin_amdgcn_mfma_f32_16x16x32_bf16(ah[kc], Bh[g][kc], acc[g], 0, 0, 0);
                        acc[g] = __builtin_amdgcn_mfma_f32_16x16x32_bf16(al[kc], Bh[g][kc], acc[g], 0, 0, 0);
                        acc[g] = __builtin_amdgcn_mfma_f32_16x16x32_bf16(ah[kc], Bl[g][kc], acc[g], 0, 0, 0);
                    }
                float hn[4];
                gates4(acc, c0, hn);
                int hq = wv >> 1;                       // h0 chunk
                int k  = (wv & 1) * 16 + fc;            // k within chunk
                write_h(&SMEM[H0H + ((1 - p) * 2 + hq) * 512],
                        &SMEM[H0L + ((1 - p) * 2 + hq) * 512], k, fr, hn);
            }
            __syncthreads();
        }
    } else if (wv < 6) {
        // =================== layer1 role (waves 4,5) ===================
        s8v Bh[4][3], Bl[4][3];
        float bias[4];
#pragma unroll
        for (int g = 0; g < 4; ++g) {
            int n = g * 32 + (wv & 1) * 16 + fc;
            bias[g] = b1[n];
#pragma unroll
            for (int kc = 0; kc < 3; ++kc)
                load_bfrag(W1, U1, 64, 96, 128, kc * 32 + fr * 8, n, Bh[g][kc], Bl[g][kc]);
        }
        float c1[4] = {0.f, 0.f, 0.f, 0.f};
        __syncthreads();                                // barrier #2
        for (int s = 0; s < T_STEPS + 2; ++s) {
            if (s >= 1 && s <= T_STEPS) {
                int p = s & 1;
                s8v ah[3], al[3];
                ah[0] = *(const s8v*)&SMEM[H0H + (p * 2 + 0) * 512 + lane * 8];
                al[0] = *(const s8v*)&SMEM[H0L + (p * 2 + 0) * 512 + lane * 8];
                ah[1] = *(const s8v*)&SMEM[H0H + (p * 2 + 1) * 512 + lane * 8];
                al[1] = *(const s8v*)&SMEM[H0L + (p * 2 + 1) * 512 + lane * 8];
                ah[2] = *(const s8v*)&SMEM[H1H + p * 512 + lane * 8];
                al[2] = *(const s8v*)&SMEM[H1L + p * 512 + lane * 8];
                f4v acc[4];
#pragma unroll
                for (int g = 0; g < 4; ++g) acc[g] = (f4v){bias[g], bias[g], bias[g], bias[g]};
#pragma unroll
                for (int kc = 0; kc < 3; ++kc)
#pragma unroll
                    for (int g = 0; g < 4; ++g) {
                        acc[g] = __builtin_amdgcn_mfma_f32_16x16x32_bf16(ah[kc], Bh[g][kc], acc[g], 0, 0, 0);
                        acc[g] = __builtin_amdgcn_mfma_f32_16x16x32_bf16(al[kc], Bh[g][kc], acc[g], 0, 0, 0);
                        acc[g] = __builtin_amdgcn_mfma_f32_16x16x32_bf16(ah[kc], Bl[g][kc], acc[g], 0, 0, 0);
                    }
                float hn[4];
                gates4(acc, c1, hn);
                int k = (wv & 1) * 16 + fc;
                write_h(&SMEM[H1H + (1 - p) * 512],
                        &SMEM[H1L + (1 - p) * 512], k, fr, hn);
            }
            __syncthreads();
        }
    } else if (wv == 6) {
        // =================== layer2 role (wave 6) ===================
        s8v Bh[4][2], Bl[4][2];
        float bias[4];
#pragma unroll
        for (int g = 0; g < 4; ++g) {
            int n = g * 16 + fc;
            bias[g] = b2[n];
#pragma unroll
            for (int kc = 0; kc < 2; ++kc)
                load_bfrag(W2, U2, 32, 48, 64, kc * 32 + fr * 8, n, Bh[g][kc], Bl[g][kc]);
        }
        float c2[4] = {0.f, 0.f, 0.f, 0.f};
        __syncthreads();                                // barrier #2
        for (int s = 0; s < T_STEPS + 2; ++s) {
            if (s >= 2) {
                int p = s & 1;
                s8v ah[2], al[2];
                ah[0] = *(const s8v*)&SMEM[H1H + p * 512 + lane * 8];
                al[0] = *(const s8v*)&SMEM[H1L + p * 512 + lane * 8];
                ah[1] = *(const s8v*)&SMEM[H2H + p * 512 + lane * 8];
                al[1] = *(const s8v*)&SMEM[H2L + p * 512 + lane * 8];
                f4v acc[4];
#pragma unroll
                for (int g = 0; g < 4; ++g) acc[g] = (f4v){bias[g], bias[g], bias[g], bias[g]};
#pragma unroll
                for (int kc = 0; kc < 2; ++kc)
#pragma unroll
                    for (int g = 0; g < 4; ++g) {
                        acc[g] = __builtin_amdgcn_mfma_f32_16x16x32_bf16(ah[kc], Bh[g][kc], acc[g], 0, 0, 0);
                        acc[g] = __builtin_amdgcn_mfma_f32_16x16x32_bf16(al[kc], Bh[g][kc], acc[g], 0, 0, 0);
                        acc[g] = __builtin_amdgcn_mfma_f32_16x16x32_bf16(ah[kc], Bl[g][kc], acc[g], 0, 0, 0);
                    }
                float hn[4];
                gates4(acc, c2, hn);
                write_h(&SMEM[H2H + (1 - p) * 512],
                        &SMEM[H2L + (1 - p) * 512], fc, fr, hn);
                if (s == T_STEPS + 1 && fr < 2) {       // t2 = 255: final h2
#pragma unroll
                    for (int r = 0; r < 4; ++r) h2last[fr * 4 + r][fc] = hn[r];
                }
            }
            __syncthreads();
        }
    } else {
        // =================== x-stager role (wave 7) ===================
        const int xb = lane >> 3;                       // batch row 0..7
        const int fo = (lane & 7) * 8;                  // feature octet base
        const float* xp = x + ((size_t)(bbase + xb) * T_STEPS) * 64 + fo;
        const int c_  = fo >> 5;                        // x chunk 0/1
        const int kg  = (fo & 31) >> 3;                 // k-group in chunk
        const int o_  = (kg * 16 + xb) * 8;             // element offset

        auto stage = [&](int t) {
            float4 v0 = *(const float4*)(xp + (size_t)t * 64);
            float4 v1 = *(const float4*)(xp + (size_t)t * 64 + 4);
            float vv[8] = {v0.x, v0.y, v0.z, v0.w, v1.x, v1.y, v1.z, v1.w};
            s8v hi8, lo8;
#pragma unroll
            for (int j = 0; j < 8; ++j) {
                unsigned short h = f2bf(vv[j]);
                hi8[j] = (short)h;
                lo8[j] = (short)f2bf(vv[j] - bf2f(h));
            }
            int buf = t & 1;
            *(s8v*)&SMEM[XH + (buf * 2 + c_) * 512 + o_] = hi8;
            *(s8v*)&SMEM[XL + (buf * 2 + c_) * 512 + o_] = lo8;
        };
        stage(0);                                       // prologue: x(0) -> parity 0
        __syncthreads();                                // barrier #2
        for (int s = 0; s < T_STEPS + 2; ++s) {
            if (s <= T_STEPS - 2) stage(s + 1);
            __syncthreads();
        }
    }

    // =================== dense head ===================
    if (tid < BT) {
        float acc = bd[0];
#pragma unroll
        for (int j = 0; j < 16; ++j) acc += h2last[tid][j] * Wd[j];
        out[bbase + tid] = acc;
    }
}

extern "C" void kernel_launch(void* const* d_in, const int* in_sizes, int n_in,
                              void* d_out, int out_size, void* d_ws, size_t ws_size,
                              hipStream_t stream) {
    (void)in_sizes; (void)n_in; (void)d_ws; (void)ws_size; (void)out_size;
    const float* x  = (const float*)d_in[0];
    const float* W0 = (const float*)d_in[1];
    const float* U0 = (const float*)d_in[2];
    const float* b0 = (const float*)d_in[3];
    const float* W1 = (const float*)d_in[4];
    const float* U1 = (const float*)d_in[5];
    const float* b1 = (const float*)d_in[6];
    const float* W2 = (const float*)d_in[7];
    const float* U2 = (const float*)d_in[8];
    const float* b2 = (const float*)d_in[9];
    const float* Wd = (const float*)d_in[10];
    const float* bd = (const float*)d_in[11];
    float* out = (float*)d_out;

    dim3 grid(2048 / BT);   // 256 blocks, 1 per CU
    dim3 block(512);        // 8 waves, 2 per SIMD
    hipLaunchKernelGGL(lstm_pipe, grid, block, 0, stream,
                       x, W0, U0, b0, W1, U1, b1, W2, U2, b2, Wd, bd, out);
}